// Round 14
// baseline (228.466 us; speedup 1.0000x reference)
//
#include <hip/hip_runtime.h>
#include <hip/hip_bf16.h>
#include <stdint.h>

typedef short bf16x8 __attribute__((ext_vector_type(8)));
typedef float f32x4 __attribute__((ext_vector_type(4)));
typedef unsigned int u32x2 __attribute__((ext_vector_type(2)));
typedef unsigned short u16;

// ---- helpers -------------------------------------------------------------

__device__ __forceinline__ u16 f2bf_bits(float f) {
    __hip_bfloat16 h = __float2bfloat16(f);
    return __builtin_bit_cast(u16, h);
}

// pack two floats to bf16 pair (round-half-up): low = a, high = b
__device__ __forceinline__ uint32_t pack2bf(float a, float b) {
    uint32_t ua = __builtin_bit_cast(uint32_t, a) + 0x8000u;
    uint32_t ub = __builtin_bit_cast(uint32_t, b) + 0x8000u;
    return __builtin_amdgcn_perm(ub, ua, 0x07060302u);
}

// async global->LDS, 16B per lane; LDS dest = wave-uniform base + lane*16
__device__ __forceinline__ void gld_lds16(const void* g, void* l) {
    __builtin_amdgcn_global_load_lds(
        (const __attribute__((address_space(1))) void*)g,
        (__attribute__((address_space(3))) void*)l, 16, 0, 0);
}

#define CEXP 0.18033688011112042f  // log2(e)/8 : exp(s/8) = exp2(s*CEXP)

// ---- fused cast kernel ---------------------------------------------------
// region A: x (1,572,864 float4) ; region B: wq|wk|wv|wo (589,824 float4)
// Outputs kept TEMPORAL: xb/Wf are re-read by the immediately-following QKV
// GEMM (L3-resident either way; no reason to hint eviction).

__global__ __launch_bounds__(256) void cast_all_kernel(
    const float* __restrict__ x, const float* __restrict__ w0,
    const float* __restrict__ w1, const float* __restrict__ w2,
    const float* __restrict__ w3, u16* __restrict__ xb,
    u16* __restrict__ o0, u16* __restrict__ o1,
    u16* __restrict__ o2, u16* __restrict__ o3,
    const float* __restrict__ bq, const float* __restrict__ bk,
    const float* __restrict__ bv, float* __restrict__ biasf) {
    int gid = blockIdx.x * 256 + threadIdx.x;
    const float* s;
    u16* d;
    int off;
    if (gid < 1572864) {
        s = x; d = xb; off = gid;
    } else {
        int g2 = gid - 1572864;
        int which = g2 / 147456;
        off = g2 - which * 147456;
        s = which == 0 ? w0 : which == 1 ? w1 : which == 2 ? w2 : w3;
        d = which == 0 ? o0 : which == 1 ? o1 : which == 2 ? o2 : o3;
    }
    float4 v = ((const float4*)s)[off];
    ushort4 u;
    u.x = f2bf_bits(v.x); u.y = f2bf_bits(v.y);
    u.z = f2bf_bits(v.z); u.w = f2bf_bits(v.w);
    ((ushort4*)d)[off] = u;
    if (gid < 2304) {
        float bb = gid < 768 ? bq[gid] : gid < 1536 ? bk[gid - 768] : bv[gid - 1536];
        biasf[gid] = bb;
    }
}

// ---- GEMM: C[m,n] = sum_k X[m,k]*W[n,k] + bias[n]  (both row-major in K)
// R8 structure (verified best): BK=64, single 32KB buffer, 2 barriers/kt,
// XCD-chunked bijective swizzle, m-major tiles, gld_lds16 async staging.
// MODE 2 folds the softmax scale CEXP into Q columns (c0 < 768).
// R14: bulk outputs stored NON-TEMPORAL. QKV writes 43MB of lines that are
// only read by a LATER kernel (different XCD mapping; 63MB > 32MB aggregate
// L2) -- with write-allocate they evict the hot per-XCD read set (W panel
// 3.5MB + xb m-bands) that the latency-bound stage loads depend on. nt
// keeps coherence (kernel-boundary writeback) without the displacement.
// LDS rows 128B = 8 chunks of 16B; slot(row,c) = c ^ ((row ^ (row>>3)) & 7)
// MODE: 0 = bf16 out, 1 = f32 out, 2 = QKV fused (V n-tiles -> Vt transposed)

template <int RT, int MODE>
__global__ __launch_bounds__(256) void gemm_xwt(
    const u16* __restrict__ X, const u16* __restrict__ W,
    const float* __restrict__ bias, float* __restrict__ Cf,
    u16* __restrict__ Cb, u16* __restrict__ Vt, int K, int NC, int NTIL) {
    constexpr int JR = RT / 32;
    __shared__ u16 lsX[RT * 64];
    __shared__ u16 lsW[128 * 64];
    const int tid = threadIdx.x;
    const int w = tid >> 6, lane = tid & 63;
    const int quad = lane >> 4, l15 = lane & 15;
    // XCD-chunked bijective swizzle (gridDim.x % 8 == 0), m-major tiles
    const int cpx = gridDim.x >> 3;
    const int sb = (blockIdx.x & 7) * cpx + (blockIdx.x >> 3);
    const int mt = sb / NTIL, nt = sb - mt * NTIL;
    const int m0 = mt * RT, n0 = nt * 128;
    const int wr = (w >> 1) * (RT / 2), wc = (w & 1) * 64;
    const int rr = lane >> 3, c8 = lane & 7;

    f32x4 acc[JR][4];
    for (int j = 0; j < JR; ++j)
        for (int i = 0; i < 4; ++i) acc[j][i] = (f32x4){0.f, 0.f, 0.f, 0.f};

    const int KT = K / 64;
    for (int kt = 0; kt < KT; ++kt) {
        const int k0 = kt * 64;
        __syncthreads();
        for (int cb = w; cb < RT / 8; cb += 4) {
            int row = cb * 8 + rr;
            int cg = c8 ^ ((rr ^ cb) & 7);
            gld_lds16(X + (size_t)(m0 + row) * K + k0 + cg * 8, &lsX[cb * 512]);
        }
        for (int cb = w; cb < 16; cb += 4) {
            int row = cb * 8 + rr;
            int cg = c8 ^ ((rr ^ cb) & 7);
            gld_lds16(W + (size_t)(n0 + row) * K + k0 + cg * 8, &lsW[cb * 512]);
        }
        __syncthreads();

        for (int kk = 0; kk < 2; ++kk) {
            bf16x8 xf[JR], wf[4];
            for (int j = 0; j < JR; ++j) {
                int row = wr + j * 16 + l15;
                int slot = (kk * 4 + quad) ^ ((row ^ (row >> 3)) & 7);
                xf[j] = *(const bf16x8*)&lsX[row * 64 + slot * 8];
            }
            for (int i = 0; i < 4; ++i) {
                int row = wc + i * 16 + l15;
                int slot = (kk * 4 + quad) ^ ((row ^ (row >> 3)) & 7);
                wf[i] = *(const bf16x8*)&lsW[row * 64 + slot * 8];
            }
            for (int j = 0; j < JR; ++j)
                for (int i = 0; i < 4; ++i)
                    acc[j][i] = __builtin_amdgcn_mfma_f32_16x16x32_bf16(
                        wf[i], xf[j], acc[j][i], 0, 0, 0);
        }
    }

    const bool vtile = (MODE == 2) && (n0 >= 1536);
    for (int i = 0; i < 4; ++i) {
        int c0 = n0 + wc + i * 16 + quad * 4;
        float4 bv4 = *(const float4*)&bias[c0];
        for (int j = 0; j < JR; ++j) {
            int row = m0 + wr + j * 16 + l15;
            float v0 = acc[j][i][0] + bv4.x;
            float v1 = acc[j][i][1] + bv4.y;
            float v2 = acc[j][i][2] + bv4.z;
            float v3 = acc[j][i][3] + bv4.w;
            if (MODE == 1) {
                f32x4 o4 = {v0, v1, v2, v3};
                __builtin_nontemporal_store(o4, (f32x4*)&Cf[(size_t)row * NC + c0]);
            } else if (vtile) {
                // V tile: store transposed to Vt[(bh*64+d)*2048 + s]
                int d = c0 - 1536;            // 0..767 across heads
                int bq_ = row >> 11;          // batch
                int s = row & 2047;
                int h = d >> 6, dd = d & 63;
                size_t base = ((size_t)(bq_ * 12 + h) * 64 + dd) * 2048 + s;
                __builtin_nontemporal_store(f2bf_bits(v0), &Vt[base]);
                __builtin_nontemporal_store(f2bf_bits(v1), &Vt[base + 2048]);
                __builtin_nontemporal_store(f2bf_bits(v2), &Vt[base + 4096]);
                __builtin_nontemporal_store(f2bf_bits(v3), &Vt[base + 6144]);
            } else {
                // MODE 2 Q-region: fold softmax scale into Q (c0 uniform
                // per 16-col group; 768 % 16 == 0 so the test is exact)
                float sc = (MODE == 2 && c0 < 768) ? CEXP : 1.0f;
                u32x2 pk = {pack2bf(v0 * sc, v1 * sc), pack2bf(v2 * sc, v3 * sc)};
                __builtin_nontemporal_store(pk, (u32x2*)&Cb[(size_t)row * NC + c0]);
            }
        }
    }
}

// ---- flash attention, S^T formulation, fixed-max softmax -----------------
// v2: ping-pong K/V staging (2nd buffer reuses dead lsQ space, no LDS growth)
// v4: uniform-duration blocks via causal pairing (ta = j, tb = 31-j).
// v6 (R10): Q arrives pre-scaled by CEXP -> softmax is exp2(S) directly.
// R14: O stores non-temporal (read only by the later out-GEMM).

__global__ __launch_bounds__(256, 3) void attn_kernel(
    const u16* __restrict__ QKV, const u16* __restrict__ Vt, u16* __restrict__ O) {
    __shared__ u16 lsQ[128 * 64];      // 16KB: Q tiles; reused as K1|V1 after Q-frag reads
    __shared__ u16 lsK0[64 * 64];      // 8KB
    __shared__ u16 lsV0[64 * 64];      // 8KB
    __shared__ u16 lsP[4][32 * 72];    // 18KB, wave-private P staging

    int bx = blockIdx.x;               // 768 = 48 bh x 16 j
    int bh = bx % 48;
    int j  = bx / 48;                  // 0..15
    const int ta = j;                  // short q-tile (64 rows): rows ta*64..
    const int tb = 31 - j;             // long  q-tile: rows tb*64..   (ta < tb)
    int bb = bh / 12, h = bh % 12;
    int tid = threadIdx.x, w = tid >> 6, lane = tid & 63;
    int quad = lane >> 4, l15 = lane & 15;
    int rr = lane >> 3, c8 = lane & 7;

    u16* K1 = lsQ;                    // 64*64 u16 = 8KB
    u16* V1 = lsQ + 4096;             // 64*64 u16 = 8KB (exactly fills lsQ)

    const size_t kgbase = (size_t)(bb * 2048) * 2304 + 768 + (size_t)h * 64;
    const size_t vgbase = (size_t)(bh * 64) * 2048;

    // stage K/V tile kt into (lsK, lsV): 4 gld_lds16 per wave
    auto stage = [&](int kt, u16* lsK, u16* lsV) {
        for (int cb = w; cb < 8; cb += 4) {
            int row = cb * 8 + rr;
            int cg = c8 ^ ((rr ^ cb) & 7);
            gld_lds16(QKV + kgbase + (size_t)(kt * 64 + row) * 2304 + cg * 8,
                      &lsK[cb * 512]);
            gld_lds16(Vt + vgbase + (size_t)row * 2048 + kt * 64 + cg * 8,
                      &lsV[cb * 512]);
        }
    };

    // prologue: stage Q (two 64-row tiles: local rows 0-63 = ta, 64-127 = tb)
    for (int cb = w; cb < 16; cb += 4) {
        int row = cb * 8 + rr;
        int qrow = (row < 64) ? ta * 64 + row : tb * 64 + (row - 64);
        int cg = c8 ^ ((rr ^ cb) & 7);
        gld_lds16(QKV + (size_t)(bb * 2048 + qrow) * 2304 + h * 64 + cg * 8,
                  &lsQ[cb * 512]);
    }
    stage(0, lsK0, lsV0);
    __syncthreads();

    bf16x8 q0[2], q1[2];
    for (int g = 0; g < 2; ++g) {
        int rowq = g * 64 + w * 16 + l15;
        int swq = (rowq ^ (rowq >> 3)) & 7;
        q0[g] = *(const bf16x8*)&lsQ[rowq * 64 + ((0 + quad) ^ swq) * 8];
        q1[g] = *(const bf16x8*)&lsQ[rowq * 64 + ((4 + quad) ^ swq) * 8];
    }
    __syncthreads();   // all waves' Q-frag reads done before lsQ is reused as K1|V1

    f32x4 oacc0[4], oacc1[4];
    for (int dt = 0; dt < 4; ++dt) {
        oacc0[dt] = (f32x4){0.f, 0.f, 0.f, 0.f};
        oacc1[dt] = (f32x4){0.f, 0.f, 0.f, 0.f};
    }
    float li0 = 0.f, li1 = 0.f;
    u16* Pw = lsP[w];
    const int qrel = w * 16 + l15;

    auto compute = [&](int kt, const u16* lsK, const u16* lsV) {
        const bool do0 = (kt <= ta);

        f32x4 S0[4], S1[4];
        __builtin_amdgcn_s_setprio(1);
        for (int ct = 0; ct < 4; ++ct) {
            int rowk = ct * 16 + l15;
            int swk = (rowk ^ (rowk >> 3)) & 7;
            bf16x8 k0 = *(const bf16x8*)&lsK[rowk * 64 + ((0 + quad) ^ swk) * 8];
            bf16x8 k1 = *(const bf16x8*)&lsK[rowk * 64 + ((4 + quad) ^ swk) * 8];
            f32x4 z = (f32x4){0.f, 0.f, 0.f, 0.f};
            S1[ct] = __builtin_amdgcn_mfma_f32_16x16x32_bf16(k0, q0[1], z, 0, 0, 0);
            S1[ct] = __builtin_amdgcn_mfma_f32_16x16x32_bf16(k1, q1[1], S1[ct], 0, 0, 0);
            if (do0) {
                S0[ct] = __builtin_amdgcn_mfma_f32_16x16x32_bf16(k0, q0[0], z, 0, 0, 0);
                S0[ct] = __builtin_amdgcn_mfma_f32_16x16x32_bf16(k1, q1[0], S0[ct], 0, 0, 0);
            }
        }
        __builtin_amdgcn_s_setprio(0);

        if (kt == ta) {      // diagonal tile of short q-tile
            for (int ct = 0; ct < 4; ++ct) {
                int kbase = ct * 16 + quad * 4;
                for (int r = 0; r < 4; ++r)
                    if (kbase + r > qrel) S0[ct][r] = -1e30f;
            }
        }
        if (kt == tb) {      // diagonal tile of long q-tile (last iteration)
            for (int ct = 0; ct < 4; ++ct) {
                int kbase = ct * 16 + quad * 4;
                for (int r = 0; r < 4; ++r)
                    if (kbase + r > qrel) S1[ct][r] = -1e30f;
            }
        }

        if (do0) {
            u16* Pr = &Pw[(size_t)l15 * 72];
            for (int ct = 0; ct < 4; ++ct) {
                float p0 = __builtin_amdgcn_exp2f(S0[ct][0]);
                float p1 = __builtin_amdgcn_exp2f(S0[ct][1]);
                float p2 = __builtin_amdgcn_exp2f(S0[ct][2]);
                float p3 = __builtin_amdgcn_exp2f(S0[ct][3]);
                li0 += (p0 + p1) + (p2 + p3);
                uint2 pk = {pack2bf(p0, p1), pack2bf(p2, p3)};
                *(uint2*)&Pr[ct * 16 + quad * 4] = pk;
            }
        }
        {
            u16* Pr = &Pw[(size_t)(16 + l15) * 72];
            for (int ct = 0; ct < 4; ++ct) {
                float p0 = __builtin_amdgcn_exp2f(S1[ct][0]);
                float p1 = __builtin_amdgcn_exp2f(S1[ct][1]);
                float p2 = __builtin_amdgcn_exp2f(S1[ct][2]);
                float p3 = __builtin_amdgcn_exp2f(S1[ct][3]);
                li1 += (p0 + p1) + (p2 + p3);
                uint2 pk = {pack2bf(p0, p1), pack2bf(p2, p3)};
                *(uint2*)&Pr[ct * 16 + quad * 4] = pk;
            }
        }

        __builtin_amdgcn_s_setprio(1);
        for (int ks = 0; ks < 2; ++ks) {
            bf16x8 bp1 = *(const bf16x8*)&Pw[(size_t)(16 + l15) * 72 + ks * 32 + quad * 8];
            bf16x8 bp0;
            if (do0) bp0 = *(const bf16x8*)&Pw[(size_t)l15 * 72 + ks * 32 + quad * 8];
            for (int dt = 0; dt < 4; ++dt) {
                int rowv = dt * 16 + l15;
                int swv = (rowv ^ (rowv >> 3)) & 7;
                bf16x8 av = *(const bf16x8*)&lsV[rowv * 64 + ((ks * 4 + quad) ^ swv) * 8];
                oacc1[dt] = __builtin_amdgcn_mfma_f32_16x16x32_bf16(av, bp1, oacc1[dt], 0, 0, 0);
                if (do0)
                    oacc0[dt] = __builtin_amdgcn_mfma_f32_16x16x32_bf16(av, bp0, oacc0[dt], 0, 0, 0);
            }
        }
        __builtin_amdgcn_s_setprio(0);
    };

    // main loop over kt = 0..tb (trip = tb+1, 17..32, parity varies).
    for (int kt = 0; kt + 1 <= tb; kt += 2) {
        stage(kt + 1, K1, V1);
        compute(kt, lsK0, lsV0);
        __syncthreads();
        if (kt + 2 <= tb) stage(kt + 2, lsK0, lsV0);
        compute(kt + 1, K1, V1);
        __syncthreads();
    }
    if ((tb & 1) == 0) compute(tb, lsK0, lsV0);

    li0 += __shfl_xor(li0, 16, 64);
    li0 += __shfl_xor(li0, 32, 64);
    li1 += __shfl_xor(li1, 16, 64);
    li1 += __shfl_xor(li1, 32, 64);
    float inv0 = 1.0f / li0, inv1 = 1.0f / li1;

    for (int g = 0; g < 2; ++g) {
        float inv = g ? inv1 : inv0;
        f32x4* oa = g ? oacc1 : oacc0;
        int row = (g ? tb : ta) * 64 + w * 16 + l15;
        for (int dt = 0; dt < 4; ++dt) {
            u32x2 pk = {pack2bf(oa[dt][0] * inv, oa[dt][1] * inv),
                        pack2bf(oa[dt][2] * inv, oa[dt][3] * inv)};
            __builtin_nontemporal_store(
                pk, (u32x2*)&O[(size_t)(bb * 2048 + row) * 768 + h * 64 + dt * 16 + quad * 4]);
        }
    }
}

// ---- launch --------------------------------------------------------------

extern "C" void kernel_launch(void* const* d_in, const int* in_sizes, int n_in,
                              void* d_out, int out_size, void* d_ws, size_t ws_size,
                              hipStream_t stream) {
    const float* x  = (const float*)d_in[0];
    const float* wq = (const float*)d_in[1];
    const float* bq = (const float*)d_in[2];
    const float* wk = (const float*)d_in[3];
    const float* bk = (const float*)d_in[4];
    const float* wv = (const float*)d_in[5];
    const float* bv = (const float*)d_in[6];
    const float* wo = (const float*)d_in[7];
    const float* bo = (const float*)d_in[8];
    float* out = (float*)d_out;

    char* ws = (char*)d_ws;
    u16*   xb    = (u16*)(ws + 0);            // 8192x768 bf16
    u16*   Wf    = (u16*)(ws + 12582912);     // 2304x768 bf16
    u16*   wob   = (u16*)(ws + 16121856);     //  768x768 bf16
    float* biasf = (float*)(ws + 17301504);   // 2304 f32
    u16*   QKVb  = (u16*)(ws + 17310720);     // 8192x2304 bf16 (V region unused)
    u16*   Vtw   = (u16*)(ws + 55059456);     // 48x64x2048 bf16
    u16*   Ow    = (u16*)(ws + 67642368);     // 8192x768 bf16

    cast_all_kernel<<<8448, 256, 0, stream>>>(x, wq, wk, wv, wo,
                                              xb, Wf, Wf + 589824, Wf + 1179648, wob,
                                              bq, bk, bv, biasf);

    // fused QKV projection (V tiles stored transposed into Vtw)
    // 1D grid: 64 m-tiles x 18 n-tiles = 1152 = 8 x 144 (XCD-chunked swizzle)
    gemm_xwt<128, 2><<<1152, 256, 0, stream>>>(xb, Wf, biasf, nullptr, QKVb,
                                               Vtw, 768, 2304, 18);
    attn_kernel<<<768, 256, 0, stream>>>(QKVb, Vtw, Ow);
    // output projection -> fp32 d_out; 128 m-tiles x 6 n-tiles = 768 = 8 x 96
    gemm_xwt<64, 1><<<768, 256, 0, stream>>>(Ow, wob, bo, out, nullptr,
                                             nullptr, 768, 768, 6);
}

// Round 15
// 203.504 us; speedup vs baseline: 1.1227x; 1.1227x over previous
//
#include <hip/hip_runtime.h>
#include <hip/hip_bf16.h>
#include <stdint.h>

typedef short bf16x8 __attribute__((ext_vector_type(8)));
typedef float f32x4 __attribute__((ext_vector_type(4)));
typedef unsigned short u16;

// ---- helpers -------------------------------------------------------------

__device__ __forceinline__ u16 f2bf_bits(float f) {
    __hip_bfloat16 h = __float2bfloat16(f);
    return __builtin_bit_cast(u16, h);
}

// pack two floats to bf16 pair (round-half-up): low = a, high = b
__device__ __forceinline__ uint32_t pack2bf(float a, float b) {
    uint32_t ua = __builtin_bit_cast(uint32_t, a) + 0x8000u;
    uint32_t ub = __builtin_bit_cast(uint32_t, b) + 0x8000u;
    return __builtin_amdgcn_perm(ub, ua, 0x07060302u);
}

// async global->LDS, 16B per lane; LDS dest = wave-uniform base + lane*16
__device__ __forceinline__ void gld_lds16(const void* g, void* l) {
    __builtin_amdgcn_global_load_lds(
        (const __attribute__((address_space(1))) void*)g,
        (__attribute__((address_space(3))) void*)l, 16, 0, 0);
}

#define CEXP 0.18033688011112042f  // log2(e)/8 : exp(s/8) = exp2(s*CEXP)

// ---- fused cast kernel ---------------------------------------------------
// region A: x (1,572,864 float4) ; region B: wq|wk|wv|wo (589,824 float4)
// FINAL (R15 = R13, verified 204.5us). Session notes:
// - R12 cast-elimination (reg-staged f32 GEMMs): QKV 54->120us. gld_lds16
//   async DMA hides latency that sync load->pack->ds_write exposes.
// - R14 non-temporal outputs: QKV 55->67us. L2 write-allocate is a
//   write-combining buffer for the scattered Vt stores; nt defeats it
//   (WRITE_SIZE 43->58MB) and backpressures stage loads.

__global__ __launch_bounds__(256) void cast_all_kernel(
    const float* __restrict__ x, const float* __restrict__ w0,
    const float* __restrict__ w1, const float* __restrict__ w2,
    const float* __restrict__ w3, u16* __restrict__ xb,
    u16* __restrict__ o0, u16* __restrict__ o1,
    u16* __restrict__ o2, u16* __restrict__ o3,
    const float* __restrict__ bq, const float* __restrict__ bk,
    const float* __restrict__ bv, float* __restrict__ biasf) {
    int gid = blockIdx.x * 256 + threadIdx.x;
    const float* s;
    u16* d;
    int off;
    if (gid < 1572864) {
        s = x; d = xb; off = gid;
    } else {
        int g2 = gid - 1572864;
        int which = g2 / 147456;
        off = g2 - which * 147456;
        s = which == 0 ? w0 : which == 1 ? w1 : which == 2 ? w2 : w3;
        d = which == 0 ? o0 : which == 1 ? o1 : which == 2 ? o2 : o3;
    }
    float4 v = ((const float4*)s)[off];
    ushort4 u;
    u.x = f2bf_bits(v.x); u.y = f2bf_bits(v.y);
    u.z = f2bf_bits(v.z); u.w = f2bf_bits(v.w);
    ((ushort4*)d)[off] = u;
    if (gid < 2304) {
        float bb = gid < 768 ? bq[gid] : gid < 1536 ? bk[gid - 768] : bv[gid - 1536];
        biasf[gid] = bb;
    }
}

// ---- GEMM: C[m,n] = sum_k X[m,k]*W[n,k] + bias[n]  (both row-major in K)
// R8 structure (verified best): BK=64, single 32KB buffer, 2 barriers/kt,
// XCD-chunked bijective swizzle, m-major tiles, gld_lds16 async staging.
// MODE 2 folds the softmax scale CEXP into Q columns (c0 < 768) at the
// epilogue -- attn computes exp2(S) directly.
// LDS rows 128B = 8 chunks of 16B; slot(row,c) = c ^ ((row ^ (row>>3)) & 7)
// MODE: 0 = bf16 out, 1 = f32 out, 2 = QKV fused (V n-tiles -> Vt transposed)

template <int RT, int MODE>
__global__ __launch_bounds__(256) void gemm_xwt(
    const u16* __restrict__ X, const u16* __restrict__ W,
    const float* __restrict__ bias, float* __restrict__ Cf,
    u16* __restrict__ Cb, u16* __restrict__ Vt, int K, int NC, int NTIL) {
    constexpr int JR = RT / 32;
    __shared__ u16 lsX[RT * 64];
    __shared__ u16 lsW[128 * 64];
    const int tid = threadIdx.x;
    const int w = tid >> 6, lane = tid & 63;
    const int quad = lane >> 4, l15 = lane & 15;
    // XCD-chunked bijective swizzle (gridDim.x % 8 == 0), m-major tiles
    const int cpx = gridDim.x >> 3;
    const int sb = (blockIdx.x & 7) * cpx + (blockIdx.x >> 3);
    const int mt = sb / NTIL, nt = sb - mt * NTIL;
    const int m0 = mt * RT, n0 = nt * 128;
    const int wr = (w >> 1) * (RT / 2), wc = (w & 1) * 64;
    const int rr = lane >> 3, c8 = lane & 7;

    f32x4 acc[JR][4];
    for (int j = 0; j < JR; ++j)
        for (int i = 0; i < 4; ++i) acc[j][i] = (f32x4){0.f, 0.f, 0.f, 0.f};

    const int KT = K / 64;
    for (int kt = 0; kt < KT; ++kt) {
        const int k0 = kt * 64;
        __syncthreads();
        for (int cb = w; cb < RT / 8; cb += 4) {
            int row = cb * 8 + rr;
            int cg = c8 ^ ((rr ^ cb) & 7);
            gld_lds16(X + (size_t)(m0 + row) * K + k0 + cg * 8, &lsX[cb * 512]);
        }
        for (int cb = w; cb < 16; cb += 4) {
            int row = cb * 8 + rr;
            int cg = c8 ^ ((rr ^ cb) & 7);
            gld_lds16(W + (size_t)(n0 + row) * K + k0 + cg * 8, &lsW[cb * 512]);
        }
        __syncthreads();

        for (int kk = 0; kk < 2; ++kk) {
            bf16x8 xf[JR], wf[4];
            for (int j = 0; j < JR; ++j) {
                int row = wr + j * 16 + l15;
                int slot = (kk * 4 + quad) ^ ((row ^ (row >> 3)) & 7);
                xf[j] = *(const bf16x8*)&lsX[row * 64 + slot * 8];
            }
            for (int i = 0; i < 4; ++i) {
                int row = wc + i * 16 + l15;
                int slot = (kk * 4 + quad) ^ ((row ^ (row >> 3)) & 7);
                wf[i] = *(const bf16x8*)&lsW[row * 64 + slot * 8];
            }
            for (int j = 0; j < JR; ++j)
                for (int i = 0; i < 4; ++i)
                    acc[j][i] = __builtin_amdgcn_mfma_f32_16x16x32_bf16(
                        wf[i], xf[j], acc[j][i], 0, 0, 0);
        }
    }

    const bool vtile = (MODE == 2) && (n0 >= 1536);
    for (int i = 0; i < 4; ++i) {
        int c0 = n0 + wc + i * 16 + quad * 4;
        float4 bv4 = *(const float4*)&bias[c0];
        for (int j = 0; j < JR; ++j) {
            int row = m0 + wr + j * 16 + l15;
            float v0 = acc[j][i][0] + bv4.x;
            float v1 = acc[j][i][1] + bv4.y;
            float v2 = acc[j][i][2] + bv4.z;
            float v3 = acc[j][i][3] + bv4.w;
            if (MODE == 1) {
                float4 o4 = {v0, v1, v2, v3};
                *(float4*)&Cf[(size_t)row * NC + c0] = o4;
            } else if (vtile) {
                // V tile: store transposed to Vt[(bh*64+d)*2048 + s]
                int d = c0 - 1536;            // 0..767 across heads
                int bq_ = row >> 11;          // batch
                int s = row & 2047;
                int h = d >> 6, dd = d & 63;
                size_t base = ((size_t)(bq_ * 12 + h) * 64 + dd) * 2048 + s;
                Vt[base]          = f2bf_bits(v0);
                Vt[base + 2048]   = f2bf_bits(v1);
                Vt[base + 4096]   = f2bf_bits(v2);
                Vt[base + 6144]   = f2bf_bits(v3);
            } else {
                // MODE 2 Q-region: fold softmax scale into Q (c0 uniform
                // per 16-col group; 768 % 16 == 0 so the test is exact)
                float sc = (MODE == 2 && c0 < 768) ? CEXP : 1.0f;
                uint2 pk = {pack2bf(v0 * sc, v1 * sc), pack2bf(v2 * sc, v3 * sc)};
                *(uint2*)&Cb[(size_t)row * NC + c0] = pk;
            }
        }
    }
}

// ---- flash attention, S^T formulation, fixed-max softmax -----------------
// v2: ping-pong K/V staging (2nd buffer reuses dead lsQ space, no LDS growth)
// v4: uniform-duration blocks via causal pairing (ta = j, tb = 31-j).
// v6 (R10): Q arrives pre-scaled by CEXP -> softmax is exp2(S) directly.

__global__ __launch_bounds__(256, 3) void attn_kernel(
    const u16* __restrict__ QKV, const u16* __restrict__ Vt, u16* __restrict__ O) {
    __shared__ u16 lsQ[128 * 64];      // 16KB: Q tiles; reused as K1|V1 after Q-frag reads
    __shared__ u16 lsK0[64 * 64];      // 8KB
    __shared__ u16 lsV0[64 * 64];      // 8KB
    __shared__ u16 lsP[4][32 * 72];    // 18KB, wave-private P staging

    int bx = blockIdx.x;               // 768 = 48 bh x 16 j
    int bh = bx % 48;
    int j  = bx / 48;                  // 0..15
    const int ta = j;                  // short q-tile (64 rows): rows ta*64..
    const int tb = 31 - j;             // long  q-tile: rows tb*64..   (ta < tb)
    int bb = bh / 12, h = bh % 12;
    int tid = threadIdx.x, w = tid >> 6, lane = tid & 63;
    int quad = lane >> 4, l15 = lane & 15;
    int rr = lane >> 3, c8 = lane & 7;

    u16* K1 = lsQ;                    // 64*64 u16 = 8KB
    u16* V1 = lsQ + 4096;             // 64*64 u16 = 8KB (exactly fills lsQ)

    const size_t kgbase = (size_t)(bb * 2048) * 2304 + 768 + (size_t)h * 64;
    const size_t vgbase = (size_t)(bh * 64) * 2048;

    // stage K/V tile kt into (lsK, lsV): 4 gld_lds16 per wave
    auto stage = [&](int kt, u16* lsK, u16* lsV) {
        for (int cb = w; cb < 8; cb += 4) {
            int row = cb * 8 + rr;
            int cg = c8 ^ ((rr ^ cb) & 7);
            gld_lds16(QKV + kgbase + (size_t)(kt * 64 + row) * 2304 + cg * 8,
                      &lsK[cb * 512]);
            gld_lds16(Vt + vgbase + (size_t)row * 2048 + kt * 64 + cg * 8,
                      &lsV[cb * 512]);
        }
    };

    // prologue: stage Q (two 64-row tiles: local rows 0-63 = ta, 64-127 = tb)
    for (int cb = w; cb < 16; cb += 4) {
        int row = cb * 8 + rr;
        int qrow = (row < 64) ? ta * 64 + row : tb * 64 + (row - 64);
        int cg = c8 ^ ((rr ^ cb) & 7);
        gld_lds16(QKV + (size_t)(bb * 2048 + qrow) * 2304 + h * 64 + cg * 8,
                  &lsQ[cb * 512]);
    }
    stage(0, lsK0, lsV0);
    __syncthreads();

    bf16x8 q0[2], q1[2];
    for (int g = 0; g < 2; ++g) {
        int rowq = g * 64 + w * 16 + l15;
        int swq = (rowq ^ (rowq >> 3)) & 7;
        q0[g] = *(const bf16x8*)&lsQ[rowq * 64 + ((0 + quad) ^ swq) * 8];
        q1[g] = *(const bf16x8*)&lsQ[rowq * 64 + ((4 + quad) ^ swq) * 8];
    }
    __syncthreads();   // all waves' Q-frag reads done before lsQ is reused as K1|V1

    f32x4 oacc0[4], oacc1[4];
    for (int dt = 0; dt < 4; ++dt) {
        oacc0[dt] = (f32x4){0.f, 0.f, 0.f, 0.f};
        oacc1[dt] = (f32x4){0.f, 0.f, 0.f, 0.f};
    }
    float li0 = 0.f, li1 = 0.f;
    u16* Pw = lsP[w];
    const int qrel = w * 16 + l15;

    auto compute = [&](int kt, const u16* lsK, const u16* lsV) {
        const bool do0 = (kt <= ta);

        f32x4 S0[4], S1[4];
        __builtin_amdgcn_s_setprio(1);
        for (int ct = 0; ct < 4; ++ct) {
            int rowk = ct * 16 + l15;
            int swk = (rowk ^ (rowk >> 3)) & 7;
            bf16x8 k0 = *(const bf16x8*)&lsK[rowk * 64 + ((0 + quad) ^ swk) * 8];
            bf16x8 k1 = *(const bf16x8*)&lsK[rowk * 64 + ((4 + quad) ^ swk) * 8];
            f32x4 z = (f32x4){0.f, 0.f, 0.f, 0.f};
            S1[ct] = __builtin_amdgcn_mfma_f32_16x16x32_bf16(k0, q0[1], z, 0, 0, 0);
            S1[ct] = __builtin_amdgcn_mfma_f32_16x16x32_bf16(k1, q1[1], S1[ct], 0, 0, 0);
            if (do0) {
                S0[ct] = __builtin_amdgcn_mfma_f32_16x16x32_bf16(k0, q0[0], z, 0, 0, 0);
                S0[ct] = __builtin_amdgcn_mfma_f32_16x16x32_bf16(k1, q1[0], S0[ct], 0, 0, 0);
            }
        }
        __builtin_amdgcn_s_setprio(0);

        if (kt == ta) {      // diagonal tile of short q-tile
            for (int ct = 0; ct < 4; ++ct) {
                int kbase = ct * 16 + quad * 4;
                for (int r = 0; r < 4; ++r)
                    if (kbase + r > qrel) S0[ct][r] = -1e30f;
            }
        }
        if (kt == tb) {      // diagonal tile of long q-tile (last iteration)
            for (int ct = 0; ct < 4; ++ct) {
                int kbase = ct * 16 + quad * 4;
                for (int r = 0; r < 4; ++r)
                    if (kbase + r > qrel) S1[ct][r] = -1e30f;
            }
        }

        if (do0) {
            u16* Pr = &Pw[(size_t)l15 * 72];
            for (int ct = 0; ct < 4; ++ct) {
                float p0 = __builtin_amdgcn_exp2f(S0[ct][0]);
                float p1 = __builtin_amdgcn_exp2f(S0[ct][1]);
                float p2 = __builtin_amdgcn_exp2f(S0[ct][2]);
                float p3 = __builtin_amdgcn_exp2f(S0[ct][3]);
                li0 += (p0 + p1) + (p2 + p3);
                uint2 pk = {pack2bf(p0, p1), pack2bf(p2, p3)};
                *(uint2*)&Pr[ct * 16 + quad * 4] = pk;
            }
        }
        {
            u16* Pr = &Pw[(size_t)(16 + l15) * 72];
            for (int ct = 0; ct < 4; ++ct) {
                float p0 = __builtin_amdgcn_exp2f(S1[ct][0]);
                float p1 = __builtin_amdgcn_exp2f(S1[ct][1]);
                float p2 = __builtin_amdgcn_exp2f(S1[ct][2]);
                float p3 = __builtin_amdgcn_exp2f(S1[ct][3]);
                li1 += (p0 + p1) + (p2 + p3);
                uint2 pk = {pack2bf(p0, p1), pack2bf(p2, p3)};
                *(uint2*)&Pr[ct * 16 + quad * 4] = pk;
            }
        }

        __builtin_amdgcn_s_setprio(1);
        for (int ks = 0; ks < 2; ++ks) {
            bf16x8 bp1 = *(const bf16x8*)&Pw[(size_t)(16 + l15) * 72 + ks * 32 + quad * 8];
            bf16x8 bp0;
            if (do0) bp0 = *(const bf16x8*)&Pw[(size_t)l15 * 72 + ks * 32 + quad * 8];
            for (int dt = 0; dt < 4; ++dt) {
                int rowv = dt * 16 + l15;
                int swv = (rowv ^ (rowv >> 3)) & 7;
                bf16x8 av = *(const bf16x8*)&lsV[rowv * 64 + ((ks * 4 + quad) ^ swv) * 8];
                oacc1[dt] = __builtin_amdgcn_mfma_f32_16x16x32_bf16(av, bp1, oacc1[dt], 0, 0, 0);
                if (do0)
                    oacc0[dt] = __builtin_amdgcn_mfma_f32_16x16x32_bf16(av, bp0, oacc0[dt], 0, 0, 0);
            }
        }
        __builtin_amdgcn_s_setprio(0);
    };

    // main loop over kt = 0..tb (trip = tb+1, 17..32, parity varies).
    for (int kt = 0; kt + 1 <= tb; kt += 2) {
        stage(kt + 1, K1, V1);
        compute(kt, lsK0, lsV0);
        __syncthreads();
        if (kt + 2 <= tb) stage(kt + 2, lsK0, lsV0);
        compute(kt + 1, K1, V1);
        __syncthreads();
    }
    if ((tb & 1) == 0) compute(tb, lsK0, lsV0);

    li0 += __shfl_xor(li0, 16, 64);
    li0 += __shfl_xor(li0, 32, 64);
    li1 += __shfl_xor(li1, 16, 64);
    li1 += __shfl_xor(li1, 32, 64);
    float inv0 = 1.0f / li0, inv1 = 1.0f / li1;

    for (int g = 0; g < 2; ++g) {
        float inv = g ? inv1 : inv0;
        f32x4* oa = g ? oacc1 : oacc0;
        int row = (g ? tb : ta) * 64 + w * 16 + l15;
        for (int dt = 0; dt < 4; ++dt) {
            uint2 pk = {pack2bf(oa[dt][0] * inv, oa[dt][1] * inv),
                        pack2bf(oa[dt][2] * inv, oa[dt][3] * inv)};
            *(uint2*)&O[(size_t)(bb * 2048 + row) * 768 + h * 64 + dt * 16 + quad * 4] = pk;
        }
    }
}

// ---- launch --------------------------------------------------------------

extern "C" void kernel_launch(void* const* d_in, const int* in_sizes, int n_in,
                              void* d_out, int out_size, void* d_ws, size_t ws_size,
                              hipStream_t stream) {
    const float* x  = (const float*)d_in[0];
    const float* wq = (const float*)d_in[1];
    const float* bq = (const float*)d_in[2];
    const float* wk = (const float*)d_in[3];
    const float* bk = (const float*)d_in[4];
    const float* wv = (const float*)d_in[5];
    const float* bv = (const float*)d_in[6];
    const float* wo = (const float*)d_in[7];
    const float* bo = (const float*)d_in[8];
    float* out = (float*)d_out;

    char* ws = (char*)d_ws;
    u16*   xb    = (u16*)(ws + 0);            // 8192x768 bf16
    u16*   Wf    = (u16*)(ws + 12582912);     // 2304x768 bf16
    u16*   wob   = (u16*)(ws + 16121856);     //  768x768 bf16
    float* biasf = (float*)(ws + 17301504);   // 2304 f32
    u16*   QKVb  = (u16*)(ws + 17310720);     // 8192x2304 bf16 (V region unused)
    u16*   Vtw   = (u16*)(ws + 55059456);     // 48x64x2048 bf16
    u16*   Ow    = (u16*)(ws + 67642368);     // 8192x768 bf16

    cast_all_kernel<<<8448, 256, 0, stream>>>(x, wq, wk, wv, wo,
                                              xb, Wf, Wf + 589824, Wf + 1179648, wob,
                                              bq, bk, bv, biasf);

    // fused QKV projection (V tiles stored transposed into Vtw)
    // 1D grid: 64 m-tiles x 18 n-tiles = 1152 = 8 x 144 (XCD-chunked swizzle)
    gemm_xwt<128, 2><<<1152, 256, 0, stream>>>(xb, Wf, biasf, nullptr, QKVb,
                                               Vtw, 768, 2304, 18);
    attn_kernel<<<768, 256, 0, stream>>>(QKVb, Vtw, Ow);
    // output projection -> fp32 d_out; 128 m-tiles x 6 n-tiles = 768 = 8 x 96
    gemm_xwt<64, 1><<<768, 256, 0, stream>>>(Ow, wob, bo, out, nullptr,
                                             nullptr, 768, 768, 6);
}